// Round 1
// baseline (296.124 us; speedup 1.0000x reference)
//
#include <hip/hip_runtime.h>
#include <hip/hip_bf16.h>
#include <math.h>

#define CC   128          // channels
#define HWN  16384        // H*W
#define EE   4            // experts
#define RR   64           // rank
#define TP   64           // pixels per tile in k_experts
#define NT   (HWN / TP)   // 256 tiles per batch image

typedef __attribute__((ext_vector_type(8))) short short8;
typedef __attribute__((ext_vector_type(4))) float f32x4;

// ---------- helpers ----------
__device__ __forceinline__ unsigned short f2bf(float f) {
    __hip_bfloat16 h = __float2bfloat16(f);
    return *reinterpret_cast<unsigned short*>(&h);
}
__device__ __forceinline__ unsigned pk2bf(float lo, float hi) {
    return (unsigned)f2bf(lo) | ((unsigned)f2bf(hi) << 16);
}
__device__ __forceinline__ float gelu_exact(float v) {
    return 0.5f * v * (1.0f + erff(v * 0.7071067811865475f));
}
__device__ __forceinline__ float silu_f(float v) {
    return v / (1.0f + expf(-v));
}

// ======================================================================
// k_prep: (a) LDS-free depthwise-3x3-highpass -> gelu -> mean + plain mean
//         (b) weight bf16 conversion + proj-fold into W2
//         (c) transpose+pack x/sh -> bf16 scratch INSIDE out:
//             word (b,d,p) = (bf16 ch 2d | bf16 ch 2d+1) of x (d<64) / sh (d>=64)
//             race-free: each expert tile reads exactly the words it overwrites
// ======================================================================
#define PREP_CONV 1024
#define PREP_WCV  (PREP_CONV + 128)    // 128 convert blocks
#define PREP_WF   (PREP_WCV + 128)     // 128 fold blocks
#define PREP_TR   (PREP_WF + 1024)     // 1024 transpose-pack blocks
#define PREP_GRID (PREP_TR + 48)       // 48 mlp-warm blocks
__global__ __launch_bounds__(256) void k_prep(
    const float* __restrict__ x,   const float* __restrict__ sh,
    const float* __restrict__ proj,
    const float* __restrict__ ew0, const float* __restrict__ ew1,
    const float* __restrict__ ew2,
    const float* __restrict__ mw1, const float* __restrict__ mw2,
    const float* __restrict__ gw,  const float* __restrict__ fgw,
    float* __restrict__ fe0, float* __restrict__ pooled,
    unsigned short* __restrict__ projb, unsigned short* __restrict__ w0b,
    unsigned short* __restrict__ w1b,   unsigned short* __restrict__ w2pb,
    float* __restrict__ outw, float* __restrict__ dummy)
{
    __shared__ float wred[8];
    const int bx = blockIdx.x, tid = threadIdx.x;

    if (bx < PREP_CONV) {
        // ---- conv + pool for image bc, rolling 3-row window, no LDS ----
        const int bc = bx;
        const float* base = x + (size_t)bc * HWN;
        const int r  = tid >> 1;
        const int c0 = (tid & 1) << 6;
        const float* rm = base + r * 128 + c0;
        const float* rt = rm - 128;
        const float* rb = rm + 128;
        const bool hT = (r > 0), hB = (r < 127);
        float tl, ml, bl;
        if (c0 == 0) { tl = ml = bl = 0.f; }
        else         { tl = hT ? rt[-1] : 0.f; ml = rm[-1]; bl = hB ? rb[-1] : 0.f; }
        float4 tC = hT ? ((const float4*)rt)[0] : (float4){0.f,0.f,0.f,0.f};
        float4 mC = ((const float4*)rm)[0];
        float4 bC = hB ? ((const float4*)rb)[0] : (float4){0.f,0.f,0.f,0.f};
        float sg = 0.f, sx = 0.f;
        #pragma unroll
        for (int j = 0; j < 16; ++j) {
            float4 tN, mN, bN;
            if (j < 15) {
                tN = hT ? ((const float4*)rt)[j + 1] : (float4){0.f,0.f,0.f,0.f};
                mN = ((const float4*)rm)[j + 1];
                bN = hB ? ((const float4*)rb)[j + 1] : (float4){0.f,0.f,0.f,0.f};
            } else {
                float tr_ = 0.f, mr_ = 0.f, br_ = 0.f;
                if (c0 == 0) { tr_ = hT ? rt[64] : 0.f; mr_ = rm[64]; br_ = hB ? rb[64] : 0.f; }
                tN = (float4){tr_,0.f,0.f,0.f}; mN = (float4){mr_,0.f,0.f,0.f}; bN = (float4){br_,0.f,0.f,0.f};
            }
            const float tA[6] = {tl, tC.x, tC.y, tC.z, tC.w, tN.x};
            const float mA[6] = {ml, mC.x, mC.y, mC.z, mC.w, mN.x};
            const float bA[6] = {bl, bC.x, bC.y, bC.z, bC.w, bN.x};
            #pragma unroll
            for (int k = 0; k < 4; ++k) {
                float s8 = ((tA[k] + tA[k+1]) + (tA[k+2] + mA[k]))
                         + ((mA[k+2] + bA[k]) + (bA[k+1] + bA[k+2]));
                sg += gelu_exact(8.f * mA[k+1] - s8);
                sx += mA[k+1];
            }
            tl = tC.w; ml = mC.w; bl = bC.w; tC = tN; mC = mN; bC = bN;
        }
        for (int off = 32; off > 0; off >>= 1) {
            sg += __shfl_down(sg, off, 64);
            sx += __shfl_down(sx, off, 64);
        }
        if ((tid & 63) == 0) { wred[tid >> 6] = sg; wred[4 + (tid >> 6)] = sx; }
        __syncthreads();
        if (tid == 0) {
            fe0[bc]    = (wred[0] + wred[1] + wred[2] + wred[3]) * (1.f / 16384.f);
            pooled[bc] = (wred[4] + wred[5] + wred[6] + wred[7]) * (1.f / 16384.f);
        }
    } else if (bx < PREP_WCV) {
        // ---- convert proj/w0/w1 to bf16 ----
        int i = (bx - PREP_CONV) * 256 + tid;      // 0..32767
        if (i < CC * CC) projb[i] = f2bf(proj[i]);
        w0b[i] = f2bf(ew0[i]);
        w1b[i] = f2bf(ew1[i]);
    } else if (bx < PREP_WF) {
        // ---- fold proj into w2 -> bf16 ----
        const int bb = bx - PREP_WCV;              // 0..127
        const int e  = bb >> 5;
        const int d  = ((bb & 31) << 2) + (tid >> 6);
        const int r  = tid & 63;
        const float* pr = proj + d * CC;
        const float* wz = ew2 + (size_t)e * CC * RR + r;
        float a0 = 0.f, a1 = 0.f, a2 = 0.f, a3 = 0.f;
        for (int c = 0; c < CC; c += 4) {
            a0 += pr[c + 0] * wz[(c + 0) * RR];
            a1 += pr[c + 1] * wz[(c + 1) * RR];
            a2 += pr[c + 2] * wz[(c + 2) * RR];
            a3 += pr[c + 3] * wz[(c + 3) * RR];
        }
        w2pb[(e * CC + d) * RR + r] = f2bf((a0 + a1) + (a2 + a3));
    } else if (bx < PREP_TR) {
        // ---- transpose+pack x/sh -> bf16 word rows inside out ----
        const int idx = bx - PREP_WF;              // 0..1023
        const int d   = idx & 127;
        const int b   = idx >> 7;
        const float* s0 = (d < 64)
            ? x  + ((size_t)b * CC + 2 * d) * HWN
            : sh + ((size_t)b * CC + 2 * (d - 64)) * HWN;
        const float4* a4 = (const float4*)s0;
        const float4* c4 = (const float4*)(s0 + HWN);
        uint4* dst = (uint4*)((unsigned*)outw + ((size_t)b * CC + d) * HWN);
        for (int i = tid; i < HWN / 4; i += 256) {
            float4 a = a4[i], c = c4[i];
            uint4 w;
            w.x = pk2bf(a.x, c.x);
            w.y = pk2bf(a.y, c.y);
            w.z = pk2bf(a.z, c.z);
            w.w = pk2bf(a.w, c.w);
            dst[i] = w;
        }
    } else {
        // ---- warm MLP weights + gates (48 blocks) ----
        const int i = (bx - PREP_TR) * 256 + tid;    // 0..12287
        float s = 0.f;
        for (int j = i; j < CC * 2 * CC; j += 48 * 256) s += mw1[j] + mw2[j];
        if (i < CC * EE) s += gw[i] + fgw[i];
        if (s == 12345.678f) dummy[1] = s;
    }
}

// ---------- routing: MLP + softmax + top-2 (one block per batch) ----------
__global__ __launch_bounds__(256) void k_route(
    const float* __restrict__ fe0, const float* __restrict__ pooled,
    const float* __restrict__ w1, const float* __restrict__ b1,
    const float* __restrict__ w2, const float* __restrict__ b2,
    const float* __restrict__ gw, const float* __restrict__ fgw,
    float* __restrict__ gates, float* __restrict__ gsum)
{
    const int b = blockIdx.x, tid = threadIdx.x;
    __shared__ float hh[256];
    __shared__ float fe[128];
    __shared__ float lg[4];
    {
        const float* f0 = fe0 + b * CC;
        float a[8];
        #pragma unroll
        for (int j = 0; j < 8; ++j) a[j] = 0.f;
        for (int c = 0; c < CC; c += 8)
            #pragma unroll
            for (int j = 0; j < 8; ++j) a[j] += f0[c + j] * w1[(c + j) * 256 + tid];
        float acc = b1[tid] + ((a[0]+a[1]) + (a[2]+a[3])) + ((a[4]+a[5]) + (a[6]+a[7]));
        hh[tid] = gelu_exact(acc);
    }
    __syncthreads();
    if (tid < 128) {
        float a[8];
        #pragma unroll
        for (int j = 0; j < 8; ++j) a[j] = 0.f;
        for (int c = 0; c < 256; c += 8)
            #pragma unroll
            for (int j = 0; j < 8; ++j) a[j] += hh[c + j] * w2[(c + j) * 128 + tid];
        fe[tid] = b2[tid] + ((a[0]+a[1]) + (a[2]+a[3])) + ((a[4]+a[5]) + (a[6]+a[7]));
    }
    __syncthreads();
    if (tid < EE) {
        const float* pl = pooled + b * CC;
        float l0=0.f, l1=0.f, l2=0.f, l3=0.f;
        for (int c = 0; c < CC; c += 4) {
            l0 += pl[c+0] * gw[(c+0) * EE + tid] + fe[c+0] * fgw[(c+0) * EE + tid];
            l1 += pl[c+1] * gw[(c+1) * EE + tid] + fe[c+1] * fgw[(c+1) * EE + tid];
            l2 += pl[c+2] * gw[(c+2) * EE + tid] + fe[c+2] * fgw[(c+2) * EE + tid];
            l3 += pl[c+3] * gw[(c+3) * EE + tid] + fe[c+3] * fgw[(c+3) * EE + tid];
        }
        lg[tid] = (l0 + l1) + (l2 + l3);
    }
    __syncthreads();
    if (tid == 0) {
        float mx = fmaxf(fmaxf(lg[0], lg[1]), fmaxf(lg[2], lg[3]));
        float sc[EE]; float ssum = 0.f;
        for (int e = 0; e < EE; ++e) { sc[e] = expf(lg[e] - mx); ssum += sc[e]; }
        float inv = 1.f / ssum;
        for (int e = 0; e < EE; ++e) sc[e] *= inv;
        int i1 = 0;
        for (int e = 1; e < EE; ++e) if (sc[e] > sc[i1]) i1 = e;
        int i2 = -1;
        for (int e = 0; e < EE; ++e) {
            if (e == i1) continue;
            if (i2 < 0 || sc[e] > sc[i2]) i2 = e;
        }
        for (int e = 0; e < EE; ++e)
            gates[b * EE + e] = (e == i1) ? sc[i1] : (e == i2 ? sc[i2] : 0.f);
        gsum[b] = sc[i1] + sc[i2];
    }
}

// ======================================================================
// k_experts: experts + combine + proj, MFMA bf16, XOR-swizzled LDS
//   staging now reads pre-packed bf16 words from out (written by k_prep):
//   word (b,d,p): d<64 -> x channels (2d,2d+1); d>=64 -> sh channels.
//   Tile (b,P) reads only words {*, p in P} and overwrites exactly them.
// ======================================================================
__global__ __launch_bounds__(256, 4) void k_experts(
    const unsigned short* __restrict__ w0b, const unsigned short* __restrict__ w1b,
    const unsigned short* __restrict__ w2pb, const unsigned short* __restrict__ projb,
    const float* __restrict__ gates, const float* __restrict__ gsum,
    float* __restrict__ out)
{
    __shared__ __align__(16) unsigned short xs [TP * CC];  // 16384 B
    __shared__ __align__(16) unsigned short shs[TP * CC];  // 16384 B
    __shared__ __align__(16) unsigned short us [TP * RR];  //  8192 B
    const int tid  = threadIdx.x;
    const int b    = blockIdx.x >> 8;
    const int tile = blockIdx.x & (NT - 1);
    const int p0   = tile * TP;

    // ---- stage x/sh from packed scratch: coalesced uint loads, no cvt ----
    {
        const unsigned* wsrc = (const unsigned*)out + ((size_t)b * CC) * HWN + p0;
        const int p  = tid & 63;
        const int qh = tid >> 6;                    // 0..3
        #pragma unroll
        for (int it = 0; it < 4; ++it) {
            const int q  = it * 4 + qh;             // chunk 0..15 (8 channels each)
            const int sw = p * CC + ((q ^ (p & 15)) << 3);
            const unsigned* px_ = wsrc + (size_t)(q * 4) * HWN + p;
            const unsigned* ps_ = wsrc + (size_t)(64 + q * 4) * HWN + p;
            uint4 wx, wh;
            wx.x = px_[0]; wx.y = px_[HWN]; wx.z = px_[2 * HWN]; wx.w = px_[3 * HWN];
            wh.x = ps_[0]; wh.y = ps_[HWN]; wh.z = ps_[2 * HWN]; wh.w = ps_[3 * HWN];
            *(uint4*)&xs [sw] = wx;
            *(uint4*)&shs[sw] = wh;
        }
    }
    __syncthreads();

    const int wv = tid >> 6;        // wave 0..3
    const int ln = tid & 63;
    const int lp = ln & 15;         // m/n index within 16-tile
    const int lq = ln >> 4;         // quad

    f32x4 acc[2][4];                // [d-tile][p-tile], d in [wv*32, wv*32+32)
    #pragma unroll
    for (int i = 0; i < 2; ++i)
        #pragma unroll
        for (int j = 0; j < 4; ++j) acc[i][j] = (f32x4){0.f, 0.f, 0.f, 0.f};

    // ---- proj stage: acc = proj @ x  (K=128) ----
    {
        const int d0 = wv * 32;
        #pragma unroll
        for (int ks = 0; ks < 4; ++ks) {
            const int k0 = ks * 32 + lq * 8;
            const int ch = ks * 4 + lq;
            short8 a0 = *(const short8*)&projb[(d0 +      lp) * CC + k0];
            short8 a1 = *(const short8*)&projb[(d0 + 16 + lp) * CC + k0];
            #pragma unroll
            for (int pt = 0; pt < 4; ++pt) {
                short8 bf = *(const short8*)&xs[(pt * 16 + lp) * CC + ((ch ^ lp) << 3)];
                acc[0][pt] = __builtin_amdgcn_mfma_f32_16x16x32_bf16(a0, bf, acc[0][pt], 0, 0, 0);
                acc[1][pt] = __builtin_amdgcn_mfma_f32_16x16x32_bf16(a1, bf, acc[1][pt], 0, 0, 0);
            }
        }
        const float gs = gsum[b];
        #pragma unroll
        for (int i = 0; i < 2; ++i)
            #pragma unroll
            for (int j = 0; j < 4; ++j) acc[i][j] *= gs;
    }

    // ---- experts ----
    for (int e = 0; e < EE; ++e) {
        const float ge = gates[b * EE + e];
        if (ge == 0.f) continue;                       // block-uniform

        // stage A: a = W0 @ x, g = W1 @ sh  (rows wv*16..wv*16+16, K=128)
        f32x4 af[4], gf[4];
        #pragma unroll
        for (int pt = 0; pt < 4; ++pt) { af[pt] = (f32x4){0.f,0.f,0.f,0.f}; gf[pt] = (f32x4){0.f,0.f,0.f,0.f}; }
        const unsigned short* w0e = w0b + (size_t)(e * RR + wv * 16) * CC;
        const unsigned short* w1e = w1b + (size_t)(e * RR + wv * 16) * CC;
        #pragma unroll
        for (int ks = 0; ks < 4; ++ks) {
            const int k0 = ks * 32 + lq * 8;
            const int ch = ks * 4 + lq;
            short8 a0 = *(const short8*)&w0e[lp * CC + k0];
            short8 a1 = *(const short8*)&w1e[lp * CC + k0];
            #pragma unroll
            for (int pt = 0; pt < 4; ++pt) {
                const int sw = (pt * 16 + lp) * CC + ((ch ^ lp) << 3);
                short8 bx = *(const short8*)&xs [sw];
                short8 bs = *(const short8*)&shs[sw];
                af[pt] = __builtin_amdgcn_mfma_f32_16x16x32_bf16(a0, bx, af[pt], 0, 0, 0);
                gf[pt] = __builtin_amdgcn_mfma_f32_16x16x32_bf16(a1, bs, gf[pt], 0, 0, 0);
            }
        }
        __syncthreads();   // prev expert's us fully consumed
        // u = ge * a * silu(g) -> bf16 -> us (C layout row r = wv*16+lq*4+i)
        #pragma unroll
        for (int pt = 0; pt < 4; ++pt) {
            unsigned short t[4];
            #pragma unroll
            for (int i = 0; i < 4; ++i)
                t[i] = f2bf(ge * af[pt][i] * silu_f(gf[pt][i]));
            const int p = pt * 16 + lp;
            const int addr = p * RR + (((wv * 2 + (lq >> 1)) ^ (lp & 7)) << 3) + ((lq & 1) << 2);
            *(uint2*)&us[addr] = *(uint2*)t;
        }
        __syncthreads();   // us visible to all waves
        // stage B: acc += W2p[e] @ u   (K=64)
        const unsigned short* w2e = w2pb + (size_t)(e * CC + wv * 32) * RR;
        #pragma unroll
        for (int ks = 0; ks < 2; ++ks) {
            const int k0 = ks * 32 + lq * 8;
            const int ch = ks * 4 + lq;
            short8 a0 = *(const short8*)&w2e[lp * RR + k0];
            short8 a1 = *(const short8*)&w2e[(16 + lp) * RR + k0];
            #pragma unroll
            for (int pt = 0; pt < 4; ++pt) {
                short8 bu = *(const short8*)&us[(pt * 16 + lp) * RR + ((ch ^ (lp & 7)) << 3)];
                acc[0][pt] = __builtin_amdgcn_mfma_f32_16x16x32_bf16(a0, bu, acc[0][pt], 0, 0, 0);
                acc[1][pt] = __builtin_amdgcn_mfma_f32_16x16x32_bf16(a1, bu, acc[1][pt], 0, 0, 0);
            }
        }
    }

    // ---- store: lane holds (d = wv*32 + dt*16 + lq*4 + i, p = p0 + pt*16 + lp) ----
    {
        const int d0 = wv * 32;
        #pragma unroll
        for (int dt = 0; dt < 2; ++dt)
            #pragma unroll
            for (int pt = 0; pt < 4; ++pt) {
                float* ob = out + ((size_t)(b * CC + d0 + dt * 16 + lq * 4)) * HWN + p0 + pt * 16 + lp;
                #pragma unroll
                for (int i = 0; i < 4; ++i)
                    ob[(size_t)i * HWN] = acc[dt][pt][i];
            }
    }
}

// ---------- launch ----------
extern "C" void kernel_launch(void* const* d_in, const int* in_sizes, int n_in,
                              void* d_out, int out_size, void* d_ws, size_t ws_size,
                              hipStream_t stream) {
    const float* x    = (const float*)d_in[0];
    const float* shr  = (const float*)d_in[1];
    const float* mw1  = (const float*)d_in[2];
    const float* mb1  = (const float*)d_in[3];
    const float* mw2  = (const float*)d_in[4];
    const float* mb2  = (const float*)d_in[5];
    const float* gw   = (const float*)d_in[6];
    const float* fgw  = (const float*)d_in[7];
    const float* ew0  = (const float*)d_in[8];
    const float* ew1  = (const float*)d_in[9];
    const float* ew2  = (const float*)d_in[10];
    const float* pw   = (const float*)d_in[11];
    float* out = (float*)d_out;

    float* ws     = (float*)d_ws;
    float* fe0    = ws + 0;        // 1024 f
    float* pooled = ws + 1024;     // 1024 f
    float* gates  = ws + 2048;     // 32 f
    float* gsum   = ws + 2080;     // 8 f
    float* dummy  = ws + 2088;     // 8 f (+pad to 2112)
    unsigned short* projb = (unsigned short*)(ws + 2112);   // 16384 us
    unsigned short* w0b   = projb + 16384;                  // 32768 us
    unsigned short* w1b   = w0b + 32768;                    // 32768 us
    unsigned short* w2pb  = w1b + 32768;                    // 32768 us

    k_prep   <<<PREP_GRID, 256, 0, stream>>>(x, shr, pw, ew0, ew1, ew2, mw1, mw2,
                                             gw, fgw, fe0, pooled, projb, w0b, w1b, w2pb,
                                             out, dummy);
    k_route  <<<8,         256, 0, stream>>>(fe0, pooled, mw1, mb1, mw2, mb2, gw, fgw, gates, gsum);
    k_experts<<<8 * NT,    256, 0, stream>>>(w0b, w1b, w2pb, projb, gates, gsum, out);
}

// Round 2
// 259.433 us; speedup vs baseline: 1.1414x; 1.1414x over previous
//
#include <hip/hip_runtime.h>
#include <hip/hip_bf16.h>
#include <math.h>

#define CC   128          // channels
#define HWN  16384        // H*W
#define EE   4            // experts
#define RR   64           // rank
#define TP   64           // pixels per tile in k_experts
#define NT   (HWN / TP)   // 256 tiles per batch image

typedef __attribute__((ext_vector_type(8))) short short8;
typedef __attribute__((ext_vector_type(4))) float f32x4;

// ---------- helpers ----------
__device__ __forceinline__ unsigned short f2bf(float f) {
    __hip_bfloat16 h = __float2bfloat16(f);
    return *reinterpret_cast<unsigned short*>(&h);
}
__device__ __forceinline__ unsigned pk2bf(float lo, float hi) {
    return (unsigned)f2bf(lo) | ((unsigned)f2bf(hi) << 16);
}
__device__ __forceinline__ float gelu_exact(float v) {
    return 0.5f * v * (1.0f + erff(v * 0.7071067811865475f));
}
__device__ __forceinline__ float silu_f(float v) {
    return v / (1.0f + expf(-v));
}

// ======================================================================
// k_prep blocks:
//   [0,512)    conv+pack-x: per (b, ch-pair) image pair. Coalesced
//              row-streaming conv (reg rolling window, shfl for l/r
//              neighbors) fused with bf16 pack -> scratch (x read ONCE).
//   [512,1024) pack-sh: pure streaming pack of sh channel pairs.
//   then weight convert / proj-fold / mlp warm.
// Scratch word (b,d,p) inside out: d<64 -> x ch(2d,2d+1); d>=64 -> sh.
// Race-free vs k_experts: each expert tile overwrites exactly the words
// it read.
// ======================================================================
#define PREP_CVX  512
#define PREP_SHP  (PREP_CVX + 512)
#define PREP_WCV  (PREP_SHP + 128)
#define PREP_WF   (PREP_WCV + 128)
#define PREP_GRID (PREP_WF + 48)
__global__ __launch_bounds__(256) void k_prep(
    const float* __restrict__ x,   const float* __restrict__ sh,
    const float* __restrict__ proj,
    const float* __restrict__ ew0, const float* __restrict__ ew1,
    const float* __restrict__ ew2,
    const float* __restrict__ mw1, const float* __restrict__ mw2,
    const float* __restrict__ gw,  const float* __restrict__ fgw,
    float* __restrict__ fe0, float* __restrict__ pooled,
    unsigned short* __restrict__ projb, unsigned short* __restrict__ w0b,
    unsigned short* __restrict__ w1b,   unsigned short* __restrict__ w2pb,
    float* __restrict__ outw, float* __restrict__ dummy)
{
    __shared__ float wr2[2][2][4];   // [half][sg/sx][wave]
    const int bx = blockIdx.x, tid = threadIdx.x;

    if (bx < PREP_CVX) {
        // ---- conv + pack for x channel pair (2*dpr, 2*dpr+1) ----
        const int dpr  = bx & 63;
        const int b    = bx >> 6;
        const int ln   = tid & 63;
        const int wv   = tid >> 6;          // 0..3: row band
        const int half = ln >> 5;           // 0: ch 2dpr, 1: ch 2dpr+1
        const int c4   = (ln & 31) << 2;    // col start
        const float* src = x + ((size_t)(b * CC + 2 * dpr + half)) * HWN + c4;
        unsigned* dst = (unsigned*)outw + ((size_t)(b * CC + dpr)) * HWN + c4;
        const int r0 = wv << 5;

        const float4 z4 = {0.f, 0.f, 0.f, 0.f};
        float4 t4 = z4, m4, b4;
        float tl = 0.f, tr = 0.f, ml, mr, bl, br;
        if (r0 > 0) {
            t4 = *(const float4*)(src + (size_t)(r0 - 1) * 128);
            tl = __shfl(t4.w, ln - 1, 64); if ((ln & 31) == 0)  tl = 0.f;
            tr = __shfl(t4.x, ln + 1, 64); if ((ln & 31) == 31) tr = 0.f;
        }
        m4 = *(const float4*)(src + (size_t)r0 * 128);
        ml = __shfl(m4.w, ln - 1, 64); if ((ln & 31) == 0)  ml = 0.f;
        mr = __shfl(m4.x, ln + 1, 64); if ((ln & 31) == 31) mr = 0.f;

        float sg = 0.f, sx = 0.f;
        for (int g = r0; g < r0 + 32; ++g) {
            if (g + 1 < 128) {
                b4 = *(const float4*)(src + (size_t)(g + 1) * 128);
                bl = __shfl(b4.w, ln - 1, 64); if ((ln & 31) == 0)  bl = 0.f;
                br = __shfl(b4.x, ln + 1, 64); if ((ln & 31) == 31) br = 0.f;
            } else { b4 = z4; bl = 0.f; br = 0.f; }
            const float ta[6] = {tl, t4.x, t4.y, t4.z, t4.w, tr};
            const float ma[6] = {ml, m4.x, m4.y, m4.z, m4.w, mr};
            const float ba[6] = {bl, b4.x, b4.y, b4.z, b4.w, br};
            #pragma unroll
            for (int k = 0; k < 4; ++k) {
                float s8 = ((ta[k] + ta[k+1]) + (ta[k+2] + ma[k]))
                         + ((ma[k+2] + ba[k]) + (ba[k+1] + ba[k+2]));
                sg += gelu_exact(8.f * ma[k+1] - s8);
                sx += ma[k+1];
            }
            // pack mid row: A-lanes combine with B values via cross-half shfl
            float ox = __shfl(m4.x, ln ^ 32, 64);
            float oy = __shfl(m4.y, ln ^ 32, 64);
            float oz = __shfl(m4.z, ln ^ 32, 64);
            float ow = __shfl(m4.w, ln ^ 32, 64);
            if (half == 0) {
                uint4 w;
                w.x = pk2bf(m4.x, ox); w.y = pk2bf(m4.y, oy);
                w.z = pk2bf(m4.z, oz); w.w = pk2bf(m4.w, ow);
                *(uint4*)(dst + (size_t)g * 128) = w;
            }
            t4 = m4; tl = ml; tr = mr;
            m4 = b4; ml = bl; mr = br;
        }
        #pragma unroll
        for (int off = 16; off; off >>= 1) {
            sg += __shfl_xor(sg, off, 64);
            sx += __shfl_xor(sx, off, 64);
        }
        if ((ln & 31) == 0) { wr2[half][0][wv] = sg; wr2[half][1][wv] = sx; }
        __syncthreads();
        if (tid < 2) {
            float g4 = (wr2[tid][0][0] + wr2[tid][0][1]) + (wr2[tid][0][2] + wr2[tid][0][3]);
            float x4 = (wr2[tid][1][0] + wr2[tid][1][1]) + (wr2[tid][1][2] + wr2[tid][1][3]);
            fe0   [b * CC + 2 * dpr + tid] = g4 * (1.f / 16384.f);
            pooled[b * CC + 2 * dpr + tid] = x4 * (1.f / 16384.f);
        }
    } else if (bx < PREP_SHP) {
        // ---- pure streaming pack of sh channel pair -> scratch d=64+dpr ----
        const int idx = bx - PREP_CVX;     // 0..511
        const int dpr = idx & 63;
        const int b   = idx >> 6;
        const float* s0 = sh + ((size_t)b * CC + 2 * dpr) * HWN;
        const float4* a4 = (const float4*)s0;
        const float4* c4p = (const float4*)(s0 + HWN);
        uint4* dst = (uint4*)((unsigned*)outw + ((size_t)(b * CC + 64 + dpr)) * HWN);
        for (int i = tid; i < HWN / 4; i += 256) {
            float4 a = a4[i], c = c4p[i];
            uint4 w;
            w.x = pk2bf(a.x, c.x);
            w.y = pk2bf(a.y, c.y);
            w.z = pk2bf(a.z, c.z);
            w.w = pk2bf(a.w, c.w);
            dst[i] = w;
        }
    } else if (bx < PREP_WCV) {
        // ---- convert proj/w0/w1 to bf16 ----
        int i = (bx - PREP_SHP) * 256 + tid;      // 0..32767
        if (i < CC * CC) projb[i] = f2bf(proj[i]);
        w0b[i] = f2bf(ew0[i]);
        w1b[i] = f2bf(ew1[i]);
    } else if (bx < PREP_WF) {
        // ---- fold proj into w2 -> bf16 ----
        const int bb = bx - PREP_WCV;              // 0..127
        const int e  = bb >> 5;
        const int d  = ((bb & 31) << 2) + (tid >> 6);
        const int r  = tid & 63;
        const float* pr = proj + d * CC;
        const float* wz = ew2 + (size_t)e * CC * RR + r;
        float a0 = 0.f, a1 = 0.f, a2 = 0.f, a3 = 0.f;
        for (int c = 0; c < CC; c += 4) {
            a0 += pr[c + 0] * wz[(c + 0) * RR];
            a1 += pr[c + 1] * wz[(c + 1) * RR];
            a2 += pr[c + 2] * wz[(c + 2) * RR];
            a3 += pr[c + 3] * wz[(c + 3) * RR];
        }
        w2pb[(e * CC + d) * RR + r] = f2bf((a0 + a1) + (a2 + a3));
    } else {
        // ---- warm MLP weights + gates (48 blocks) ----
        const int i = (bx - PREP_WF) * 256 + tid;    // 0..12287
        float s = 0.f;
        for (int j = i; j < CC * 2 * CC; j += 48 * 256) s += mw1[j] + mw2[j];
        if (i < CC * EE) s += gw[i] + fgw[i];
        if (s == 12345.678f) dummy[1] = s;
    }
}

// ---------- routing: MLP + softmax + top-2 (one block per batch) ----------
__global__ __launch_bounds__(256) void k_route(
    const float* __restrict__ fe0, const float* __restrict__ pooled,
    const float* __restrict__ w1, const float* __restrict__ b1,
    const float* __restrict__ w2, const float* __restrict__ b2,
    const float* __restrict__ gw, const float* __restrict__ fgw,
    float* __restrict__ gates, float* __restrict__ gsum)
{
    const int b = blockIdx.x, tid = threadIdx.x;
    __shared__ float hh[256];
    __shared__ float fe[128];
    __shared__ float lg[4];
    {
        const float* f0 = fe0 + b * CC;
        float a[8];
        #pragma unroll
        for (int j = 0; j < 8; ++j) a[j] = 0.f;
        for (int c = 0; c < CC; c += 8)
            #pragma unroll
            for (int j = 0; j < 8; ++j) a[j] += f0[c + j] * w1[(c + j) * 256 + tid];
        float acc = b1[tid] + ((a[0]+a[1]) + (a[2]+a[3])) + ((a[4]+a[5]) + (a[6]+a[7]));
        hh[tid] = gelu_exact(acc);
    }
    __syncthreads();
    if (tid < 128) {
        float a[8];
        #pragma unroll
        for (int j = 0; j < 8; ++j) a[j] = 0.f;
        for (int c = 0; c < 256; c += 8)
            #pragma unroll
            for (int j = 0; j < 8; ++j) a[j] += hh[c + j] * w2[(c + j) * 128 + tid];
        fe[tid] = b2[tid] + ((a[0]+a[1]) + (a[2]+a[3])) + ((a[4]+a[5]) + (a[6]+a[7]));
    }
    __syncthreads();
    if (tid < EE) {
        const float* pl = pooled + b * CC;
        float l0=0.f, l1=0.f, l2=0.f, l3=0.f;
        for (int c = 0; c < CC; c += 4) {
            l0 += pl[c+0] * gw[(c+0) * EE + tid] + fe[c+0] * fgw[(c+0) * EE + tid];
            l1 += pl[c+1] * gw[(c+1) * EE + tid] + fe[c+1] * fgw[(c+1) * EE + tid];
            l2 += pl[c+2] * gw[(c+2) * EE + tid] + fe[c+2] * fgw[(c+2) * EE + tid];
            l3 += pl[c+3] * gw[(c+3) * EE + tid] + fe[c+3] * fgw[(c+3) * EE + tid];
        }
        lg[tid] = (l0 + l1) + (l2 + l3);
    }
    __syncthreads();
    if (tid == 0) {
        float mx = fmaxf(fmaxf(lg[0], lg[1]), fmaxf(lg[2], lg[3]));
        float sc[EE]; float ssum = 0.f;
        for (int e = 0; e < EE; ++e) { sc[e] = expf(lg[e] - mx); ssum += sc[e]; }
        float inv = 1.f / ssum;
        for (int e = 0; e < EE; ++e) sc[e] *= inv;
        int i1 = 0;
        for (int e = 1; e < EE; ++e) if (sc[e] > sc[i1]) i1 = e;
        int i2 = -1;
        for (int e = 0; e < EE; ++e) {
            if (e == i1) continue;
            if (i2 < 0 || sc[e] > sc[i2]) i2 = e;
        }
        for (int e = 0; e < EE; ++e)
            gates[b * EE + e] = (e == i1) ? sc[i1] : (e == i2 ? sc[i2] : 0.f);
        gsum[b] = sc[i1] + sc[i2];
    }
}

// ======================================================================
// k_experts: experts + combine + proj, MFMA bf16, XOR-swizzled LDS
//   staging reads pre-packed bf16 words from out (written by k_prep):
//   word (b,d,p): d<64 -> x channels (2d,2d+1); d>=64 -> sh channels.
//   Tile (b,P) reads only words {*, p in P} and overwrites exactly them.
// ======================================================================
__global__ __launch_bounds__(256, 4) void k_experts(
    const unsigned short* __restrict__ w0b, const unsigned short* __restrict__ w1b,
    const unsigned short* __restrict__ w2pb, const unsigned short* __restrict__ projb,
    const float* __restrict__ gates, const float* __restrict__ gsum,
    float* __restrict__ out)
{
    __shared__ __align__(16) unsigned short xs [TP * CC];  // 16384 B
    __shared__ __align__(16) unsigned short shs[TP * CC];  // 16384 B
    __shared__ __align__(16) unsigned short us [TP * RR];  //  8192 B
    const int tid  = threadIdx.x;
    const int b    = blockIdx.x >> 8;
    const int tile = blockIdx.x & (NT - 1);
    const int p0   = tile * TP;

    // ---- stage x/sh from packed scratch: coalesced uint loads, no cvt ----
    {
        const unsigned* wsrc = (const unsigned*)out + ((size_t)b * CC) * HWN + p0;
        const int p  = tid & 63;
        const int qh = tid >> 6;                    // 0..3
        #pragma unroll
        for (int it = 0; it < 4; ++it) {
            const int q  = it * 4 + qh;             // chunk 0..15 (8 channels each)
            const int sw = p * CC + ((q ^ (p & 15)) << 3);
            const unsigned* px_ = wsrc + (size_t)(q * 4) * HWN + p;
            const unsigned* ps_ = wsrc + (size_t)(64 + q * 4) * HWN + p;
            uint4 wx, wh;
            wx.x = px_[0]; wx.y = px_[HWN]; wx.z = px_[2 * HWN]; wx.w = px_[3 * HWN];
            wh.x = ps_[0]; wh.y = ps_[HWN]; wh.z = ps_[2 * HWN]; wh.w = ps_[3 * HWN];
            *(uint4*)&xs [sw] = wx;
            *(uint4*)&shs[sw] = wh;
        }
    }
    __syncthreads();

    const int wv = tid >> 6;        // wave 0..3
    const int ln = tid & 63;
    const int lp = ln & 15;         // m/n index within 16-tile
    const int lq = ln >> 4;         // quad

    f32x4 acc[2][4];                // [d-tile][p-tile], d in [wv*32, wv*32+32)
    #pragma unroll
    for (int i = 0; i < 2; ++i)
        #pragma unroll
        for (int j = 0; j < 4; ++j) acc[i][j] = (f32x4){0.f, 0.f, 0.f, 0.f};

    // ---- proj stage: acc = proj @ x  (K=128) ----
    {
        const int d0 = wv * 32;
        #pragma unroll
        for (int ks = 0; ks < 4; ++ks) {
            const int k0 = ks * 32 + lq * 8;
            const int ch = ks * 4 + lq;
            short8 a0 = *(const short8*)&projb[(d0 +      lp) * CC + k0];
            short8 a1 = *(const short8*)&projb[(d0 + 16 + lp) * CC + k0];
            #pragma unroll
            for (int pt = 0; pt < 4; ++pt) {
                short8 bf = *(const short8*)&xs[(pt * 16 + lp) * CC + ((ch ^ lp) << 3)];
                acc[0][pt] = __builtin_amdgcn_mfma_f32_16x16x32_bf16(a0, bf, acc[0][pt], 0, 0, 0);
                acc[1][pt] = __builtin_amdgcn_mfma_f32_16x16x32_bf16(a1, bf, acc[1][pt], 0, 0, 0);
            }
        }
        const float gs = gsum[b];
        #pragma unroll
        for (int i = 0; i < 2; ++i)
            #pragma unroll
            for (int j = 0; j < 4; ++j) acc[i][j] *= gs;
    }

    // ---- experts ----
    for (int e = 0; e < EE; ++e) {
        const float ge = gates[b * EE + e];
        if (ge == 0.f) continue;                       // block-uniform

        // stage A: a = W0 @ x, g = W1 @ sh  (rows wv*16..wv*16+16, K=128)
        f32x4 af[4], gf[4];
        #pragma unroll
        for (int pt = 0; pt < 4; ++pt) { af[pt] = (f32x4){0.f,0.f,0.f,0.f}; gf[pt] = (f32x4){0.f,0.f,0.f,0.f}; }
        const unsigned short* w0e = w0b + (size_t)(e * RR + wv * 16) * CC;
        const unsigned short* w1e = w1b + (size_t)(e * RR + wv * 16) * CC;
        #pragma unroll
        for (int ks = 0; ks < 4; ++ks) {
            const int k0 = ks * 32 + lq * 8;
            const int ch = ks * 4 + lq;
            short8 a0 = *(const short8*)&w0e[lp * CC + k0];
            short8 a1 = *(const short8*)&w1e[lp * CC + k0];
            #pragma unroll
            for (int pt = 0; pt < 4; ++pt) {
                const int sw = (pt * 16 + lp) * CC + ((ch ^ lp) << 3);
                short8 bx = *(const short8*)&xs [sw];
                short8 bs = *(const short8*)&shs[sw];
                af[pt] = __builtin_amdgcn_mfma_f32_16x16x32_bf16(a0, bx, af[pt], 0, 0, 0);
                gf[pt] = __builtin_amdgcn_mfma_f32_16x16x32_bf16(a1, bs, gf[pt], 0, 0, 0);
            }
        }
        __syncthreads();   // prev expert's us fully consumed
        // u = ge * a * silu(g) -> bf16 -> us (C layout row r = wv*16+lq*4+i)
        #pragma unroll
        for (int pt = 0; pt < 4; ++pt) {
            unsigned short t[4];
            #pragma unroll
            for (int i = 0; i < 4; ++i)
                t[i] = f2bf(ge * af[pt][i] * silu_f(gf[pt][i]));
            const int p = pt * 16 + lp;
            const int addr = p * RR + (((wv * 2 + (lq >> 1)) ^ (lp & 7)) << 3) + ((lq & 1) << 2);
            *(uint2*)&us[addr] = *(uint2*)t;
        }
        __syncthreads();   // us visible to all waves
        // stage B: acc += W2p[e] @ u   (K=64)
        const unsigned short* w2e = w2pb + (size_t)(e * CC + wv * 32) * RR;
        #pragma unroll
        for (int ks = 0; ks < 2; ++ks) {
            const int k0 = ks * 32 + lq * 8;
            const int ch = ks * 4 + lq;
            short8 a0 = *(const short8*)&w2e[lp * RR + k0];
            short8 a1 = *(const short8*)&w2e[(16 + lp) * RR + k0];
            #pragma unroll
            for (int pt = 0; pt < 4; ++pt) {
                short8 bu = *(const short8*)&us[(pt * 16 + lp) * RR + ((ch ^ (lp & 7)) << 3)];
                acc[0][pt] = __builtin_amdgcn_mfma_f32_16x16x32_bf16(a0, bu, acc[0][pt], 0, 0, 0);
                acc[1][pt] = __builtin_amdgcn_mfma_f32_16x16x32_bf16(a1, bu, acc[1][pt], 0, 0, 0);
            }
        }
    }

    // ---- store: lane holds (d = wv*32 + dt*16 + lq*4 + i, p = p0 + pt*16 + lp) ----
    {
        const int d0 = wv * 32;
        #pragma unroll
        for (int dt = 0; dt < 2; ++dt)
            #pragma unroll
            for (int pt = 0; pt < 4; ++pt) {
                float* ob = out + ((size_t)(b * CC + d0 + dt * 16 + lq * 4)) * HWN + p0 + pt * 16 + lp;
                #pragma unroll
                for (int i = 0; i < 4; ++i)
                    ob[(size_t)i * HWN] = acc[dt][pt][i];
            }
    }
}

// ---------- launch ----------
extern "C" void kernel_launch(void* const* d_in, const int* in_sizes, int n_in,
                              void* d_out, int out_size, void* d_ws, size_t ws_size,
                              hipStream_t stream) {
    const float* x    = (const float*)d_in[0];
    const float* shr  = (const float*)d_in[1];
    const float* mw1  = (const float*)d_in[2];
    const float* mb1  = (const float*)d_in[3];
    const float* mw2  = (const float*)d_in[4];
    const float* mb2  = (const float*)d_in[5];
    const float* gw   = (const float*)d_in[6];
    const float* fgw  = (const float*)d_in[7];
    const float* ew0  = (const float*)d_in[8];
    const float* ew1  = (const float*)d_in[9];
    const float* ew2  = (const float*)d_in[10];
    const float* pw   = (const float*)d_in[11];
    float* out = (float*)d_out;

    float* ws     = (float*)d_ws;
    float* fe0    = ws + 0;        // 1024 f
    float* pooled = ws + 1024;     // 1024 f
    float* gates  = ws + 2048;     // 32 f
    float* gsum   = ws + 2080;     // 8 f
    float* dummy  = ws + 2088;     // 8 f (+pad to 2112)
    unsigned short* projb = (unsigned short*)(ws + 2112);   // 16384 us
    unsigned short* w0b   = projb + 16384;                  // 32768 us
    unsigned short* w1b   = w0b + 32768;                    // 32768 us
    unsigned short* w2pb  = w1b + 32768;                    // 32768 us

    k_prep   <<<PREP_GRID, 256, 0, stream>>>(x, shr, pw, ew0, ew1, ew2, mw1, mw2,
                                             gw, fgw, fe0, pooled, projb, w0b, w1b, w2pb,
                                             out, dummy);
    k_route  <<<8,         256, 0, stream>>>(fe0, pooled, mw1, mb1, mw2, mb2, gw, fgw, gates, gsum);
    k_experts<<<8 * NT,    256, 0, stream>>>(w0b, w1b, w2pb, projb, gates, gsum, out);
}

// Round 3
// 253.779 us; speedup vs baseline: 1.1669x; 1.0223x over previous
//
#include <hip/hip_runtime.h>
#include <hip/hip_bf16.h>
#include <math.h>

#define CC   128          // channels
#define HWN  16384        // H*W
#define EE   4            // experts
#define RR   64           // rank
#define TP   64           // pixels per tile in k_experts
#define NT   (HWN / TP)   // 256 tiles per batch image

typedef __attribute__((ext_vector_type(8))) short short8;
typedef __attribute__((ext_vector_type(4))) float f32x4;

// ---------- helpers ----------
__device__ __forceinline__ unsigned short f2bf(float f) {
    __hip_bfloat16 h = __float2bfloat16(f);
    return *reinterpret_cast<unsigned short*>(&h);
}
__device__ __forceinline__ unsigned pk2bf(float lo, float hi) {
    return (unsigned)f2bf(lo) | ((unsigned)f2bf(hi) << 16);
}
__device__ __forceinline__ float gelu_exact(float v) {
    return 0.5f * v * (1.0f + erff(v * 0.7071067811865475f));
}
__device__ __forceinline__ float silu_f(float v) {
    return v / (1.0f + expf(-v));
}

// ======================================================================
// k_prep blocks (homogeneous heavy blocks, 4 per CU):
//   [0,1024): fused block for (b, ch-pair dpr, 64-row band):
//       - conv 3x3 highpass + gelu-mean + mean on x, fused with bf16
//         pack -> scratch (each lane owns BOTH channels: no pack shfl)
//       - streaming bf16 pack of sh for same rows/channels
//       - partial fe0/pooled per band -> summed in k_route
//   then: weight convert / proj-fold / mlp warm (light blocks).
// Scratch word (b,d,p) inside out: d<64 -> x ch(2d,2d+1); d>=64 -> sh.
// Race-free vs k_experts: each expert tile overwrites exactly the words
// it read.
// ======================================================================
#define PREP_CONV 1024
#define PREP_WCV  (PREP_CONV + 128)
#define PREP_WF   (PREP_WCV + 128)
#define PREP_GRID (PREP_WF + 48)
__global__ __launch_bounds__(256, 4) void k_prep(
    const float* __restrict__ x,   const float* __restrict__ sh,
    const float* __restrict__ proj,
    const float* __restrict__ ew0, const float* __restrict__ ew1,
    const float* __restrict__ ew2,
    const float* __restrict__ mw1, const float* __restrict__ mw2,
    const float* __restrict__ gw,  const float* __restrict__ fgw,
    float* __restrict__ fe0p, float* __restrict__ poolp,
    unsigned short* __restrict__ projb, unsigned short* __restrict__ w0b,
    unsigned short* __restrict__ w1b,   unsigned short* __restrict__ w2pb,
    float* __restrict__ outw, float* __restrict__ dummy)
{
    __shared__ float wr[8][4];   // [stream][sgA,sxA,sgB,sxB]
    const int bx = blockIdx.x, tid = threadIdx.x;

    if (bx < PREP_CONV) {
        const int b    = bx >> 7;
        const int dpr  = (bx & 127) >> 1;   // channel pair 0..63
        const int band = bx & 1;            // row band 0..1 (64 rows)
        const int ln   = tid & 63;
        const int wv   = tid >> 6;
        const int half = ln >> 5;
        const int l    = ln & 31;
        const int c4   = l << 2;            // col start (4 px per lane)
        const int strm = wv * 2 + half;     // 0..7 row streams
        const int r0   = band * 64 + strm * 8;

        const float* srcA = x + ((size_t)(b * CC + 2 * dpr)) * HWN + c4;
        const float* srcB = srcA + HWN;
        unsigned* dst = (unsigned*)outw + ((size_t)(b * CC + dpr)) * HWN + c4;

        const float4 z4 = {0.f, 0.f, 0.f, 0.f};
        float4 tA = z4, tB = z4, mA, mB, bA = z4, bB = z4;
        float tlA = 0.f, trA = 0.f, tlB = 0.f, trB = 0.f;
        float mlA, mrA, mlB, mrB, blA = 0.f, brA = 0.f, blB = 0.f, brB = 0.f;
        if (r0 > 0) {
            tA = *(const float4*)(srcA + (size_t)(r0 - 1) * 128);
            tB = *(const float4*)(srcB + (size_t)(r0 - 1) * 128);
            tlA = __shfl(tA.w, ln - 1, 64); if (l == 0)  tlA = 0.f;
            trA = __shfl(tA.x, ln + 1, 64); if (l == 31) trA = 0.f;
            tlB = __shfl(tB.w, ln - 1, 64); if (l == 0)  tlB = 0.f;
            trB = __shfl(tB.x, ln + 1, 64); if (l == 31) trB = 0.f;
        }
        mA = *(const float4*)(srcA + (size_t)r0 * 128);
        mB = *(const float4*)(srcB + (size_t)r0 * 128);
        mlA = __shfl(mA.w, ln - 1, 64); if (l == 0)  mlA = 0.f;
        mrA = __shfl(mA.x, ln + 1, 64); if (l == 31) mrA = 0.f;
        mlB = __shfl(mB.w, ln - 1, 64); if (l == 0)  mlB = 0.f;
        mrB = __shfl(mB.x, ln + 1, 64); if (l == 31) mrB = 0.f;

        float sgA = 0.f, sxA = 0.f, sgB = 0.f, sxB = 0.f;
        for (int g = r0; g < r0 + 8; ++g) {
            if (g + 1 < 128) {
                bA = *(const float4*)(srcA + (size_t)(g + 1) * 128);
                bB = *(const float4*)(srcB + (size_t)(g + 1) * 128);
                blA = __shfl(bA.w, ln - 1, 64); if (l == 0)  blA = 0.f;
                brA = __shfl(bA.x, ln + 1, 64); if (l == 31) brA = 0.f;
                blB = __shfl(bB.w, ln - 1, 64); if (l == 0)  blB = 0.f;
                brB = __shfl(bB.x, ln + 1, 64); if (l == 31) brB = 0.f;
            } else { bA = z4; bB = z4; blA = brA = blB = brB = 0.f; }
            {
                const float ta[6] = {tlA, tA.x, tA.y, tA.z, tA.w, trA};
                const float ma[6] = {mlA, mA.x, mA.y, mA.z, mA.w, mrA};
                const float ba[6] = {blA, bA.x, bA.y, bA.z, bA.w, brA};
                #pragma unroll
                for (int k = 0; k < 4; ++k) {
                    float s8 = ((ta[k] + ta[k+1]) + (ta[k+2] + ma[k]))
                             + ((ma[k+2] + ba[k]) + (ba[k+1] + ba[k+2]));
                    sgA += gelu_exact(8.f * ma[k+1] - s8);
                    sxA += ma[k+1];
                }
            }
            {
                const float ta[6] = {tlB, tB.x, tB.y, tB.z, tB.w, trB};
                const float ma[6] = {mlB, mB.x, mB.y, mB.z, mB.w, mrB};
                const float ba[6] = {blB, bB.x, bB.y, bB.z, bB.w, brB};
                #pragma unroll
                for (int k = 0; k < 4; ++k) {
                    float s8 = ((ta[k] + ta[k+1]) + (ta[k+2] + ma[k]))
                             + ((ma[k+2] + ba[k]) + (ba[k+1] + ba[k+2]));
                    sgB += gelu_exact(8.f * ma[k+1] - s8);
                    sxB += ma[k+1];
                }
            }
            // pack mid row (lane owns both channels -> no cross-lane)
            uint4 w;
            w.x = pk2bf(mA.x, mB.x); w.y = pk2bf(mA.y, mB.y);
            w.z = pk2bf(mA.z, mB.z); w.w = pk2bf(mA.w, mB.w);
            *(uint4*)(dst + (size_t)g * 128) = w;
            tA = mA; tlA = mlA; trA = mrA; mA = bA; mlA = blA; mrA = brA;
            tB = mB; tlB = mlB; trB = mrB; mB = bB; mlB = blB; mrB = brB;
        }
        #pragma unroll
        for (int off = 16; off; off >>= 1) {
            sgA += __shfl_xor(sgA, off, 64); sxA += __shfl_xor(sxA, off, 64);
            sgB += __shfl_xor(sgB, off, 64); sxB += __shfl_xor(sxB, off, 64);
        }
        if (l == 0) { wr[strm][0] = sgA; wr[strm][1] = sxA; wr[strm][2] = sgB; wr[strm][3] = sxB; }
        __syncthreads();
        if (tid < 4) {
            float s = 0.f;
            #pragma unroll
            for (int q = 0; q < 8; ++q) s += wr[q][tid];
            s *= (1.f / 16384.f);
            const int o = band * 1024 + b * CC + 2 * dpr;
            if (tid == 0) fe0p [o]     = s;
            if (tid == 1) poolp[o]     = s;
            if (tid == 2) fe0p [o + 1] = s;
            if (tid == 3) poolp[o + 1] = s;
        }
        // ---- sh pack for same (b, dpr, band): pure streaming ----
        {
            const float4* a4  = (const float4*)(sh + ((size_t)(b * CC + 2 * dpr)) * HWN + band * 8192);
            const float4* c4p = (const float4*)(sh + ((size_t)(b * CC + 2 * dpr + 1)) * HWN + band * 8192);
            uint4* dsts = (uint4*)((unsigned*)outw + ((size_t)(b * CC + 64 + dpr)) * HWN + band * 8192);
            for (int i = tid; i < 2048; i += 256) {
                float4 a = a4[i], c = c4p[i];
                uint4 w;
                w.x = pk2bf(a.x, c.x); w.y = pk2bf(a.y, c.y);
                w.z = pk2bf(a.z, c.z); w.w = pk2bf(a.w, c.w);
                dsts[i] = w;
            }
        }
    } else if (bx < PREP_WCV) {
        // ---- convert proj/w0/w1 to bf16 ----
        int i = (bx - PREP_CONV) * 256 + tid;      // 0..32767
        if (i < CC * CC) projb[i] = f2bf(proj[i]);
        w0b[i] = f2bf(ew0[i]);
        w1b[i] = f2bf(ew1[i]);
    } else if (bx < PREP_WF) {
        // ---- fold proj into w2 -> bf16 ----
        const int bb = bx - PREP_WCV;              // 0..127
        const int e  = bb >> 5;
        const int d  = ((bb & 31) << 2) + (tid >> 6);
        const int r  = tid & 63;
        const float* pr = proj + d * CC;
        const float* wz = ew2 + (size_t)e * CC * RR + r;
        float a0 = 0.f, a1 = 0.f, a2 = 0.f, a3 = 0.f;
        for (int c = 0; c < CC; c += 4) {
            a0 += pr[c + 0] * wz[(c + 0) * RR];
            a1 += pr[c + 1] * wz[(c + 1) * RR];
            a2 += pr[c + 2] * wz[(c + 2) * RR];
            a3 += pr[c + 3] * wz[(c + 3) * RR];
        }
        w2pb[(e * CC + d) * RR + r] = f2bf((a0 + a1) + (a2 + a3));
    } else {
        // ---- warm MLP weights + gates (48 blocks) ----
        const int i = (bx - PREP_WF) * 256 + tid;    // 0..12287
        float s = 0.f;
        for (int j = i; j < CC * 2 * CC; j += 48 * 256) s += mw1[j] + mw2[j];
        if (i < CC * EE) s += gw[i] + fgw[i];
        if (s == 12345.678f) dummy[1] = s;
    }
}

// ---------- routing: MLP + softmax + top-2 (one block per batch) ----------
__global__ __launch_bounds__(256) void k_route(
    const float* __restrict__ fe0p, const float* __restrict__ poolp,
    const float* __restrict__ w1, const float* __restrict__ b1,
    const float* __restrict__ w2, const float* __restrict__ b2,
    const float* __restrict__ gw, const float* __restrict__ fgw,
    float* __restrict__ gates, float* __restrict__ gsum)
{
    const int b = blockIdx.x, tid = threadIdx.x;
    __shared__ float hh[256];
    __shared__ float fe[128];
    __shared__ float lg[4];
    {
        const float* f0 = fe0p + b * CC;
        const float* f1 = fe0p + 1024 + b * CC;
        float a[8];
        #pragma unroll
        for (int j = 0; j < 8; ++j) a[j] = 0.f;
        for (int c = 0; c < CC; c += 8)
            #pragma unroll
            for (int j = 0; j < 8; ++j) a[j] += (f0[c + j] + f1[c + j]) * w1[(c + j) * 256 + tid];
        float acc = b1[tid] + ((a[0]+a[1]) + (a[2]+a[3])) + ((a[4]+a[5]) + (a[6]+a[7]));
        hh[tid] = gelu_exact(acc);
    }
    __syncthreads();
    if (tid < 128) {
        float a[8];
        #pragma unroll
        for (int j = 0; j < 8; ++j) a[j] = 0.f;
        for (int c = 0; c < 256; c += 8)
            #pragma unroll
            for (int j = 0; j < 8; ++j) a[j] += hh[c + j] * w2[(c + j) * 128 + tid];
        fe[tid] = b2[tid] + ((a[0]+a[1]) + (a[2]+a[3])) + ((a[4]+a[5]) + (a[6]+a[7]));
    }
    __syncthreads();
    if (tid < EE) {
        const float* pl0 = poolp + b * CC;
        const float* pl1 = poolp + 1024 + b * CC;
        float l0=0.f, l1=0.f, l2=0.f, l3=0.f;
        for (int c = 0; c < CC; c += 4) {
            l0 += (pl0[c+0]+pl1[c+0]) * gw[(c+0) * EE + tid] + fe[c+0] * fgw[(c+0) * EE + tid];
            l1 += (pl0[c+1]+pl1[c+1]) * gw[(c+1) * EE + tid] + fe[c+1] * fgw[(c+1) * EE + tid];
            l2 += (pl0[c+2]+pl1[c+2]) * gw[(c+2) * EE + tid] + fe[c+2] * fgw[(c+2) * EE + tid];
            l3 += (pl0[c+3]+pl1[c+3]) * gw[(c+3) * EE + tid] + fe[c+3] * fgw[(c+3) * EE + tid];
        }
        lg[tid] = (l0 + l1) + (l2 + l3);
    }
    __syncthreads();
    if (tid == 0) {
        float mx = fmaxf(fmaxf(lg[0], lg[1]), fmaxf(lg[2], lg[3]));
        float sc[EE]; float ssum = 0.f;
        for (int e = 0; e < EE; ++e) { sc[e] = expf(lg[e] - mx); ssum += sc[e]; }
        float inv = 1.f / ssum;
        for (int e = 0; e < EE; ++e) sc[e] *= inv;
        int i1 = 0;
        for (int e = 1; e < EE; ++e) if (sc[e] > sc[i1]) i1 = e;
        int i2 = -1;
        for (int e = 0; e < EE; ++e) {
            if (e == i1) continue;
            if (i2 < 0 || sc[e] > sc[i2]) i2 = e;
        }
        for (int e = 0; e < EE; ++e)
            gates[b * EE + e] = (e == i1) ? sc[i1] : (e == i2 ? sc[i2] : 0.f);
        gsum[b] = sc[i1] + sc[i2];
    }
}

// ======================================================================
// k_experts: experts + combine + proj, MFMA bf16, XOR-swizzled LDS
//   staging reads pre-packed bf16 words from out (written by k_prep):
//   word (b,d,p): d<64 -> x channels (2d,2d+1); d>=64 -> sh channels.
//   Tile (b,P) reads only words {*, p in P} and overwrites exactly them.
// ======================================================================
__global__ __launch_bounds__(256, 4) void k_experts(
    const unsigned short* __restrict__ w0b, const unsigned short* __restrict__ w1b,
    const unsigned short* __restrict__ w2pb, const unsigned short* __restrict__ projb,
    const float* __restrict__ gates, const float* __restrict__ gsum,
    float* __restrict__ out)
{
    __shared__ __align__(16) unsigned short xs [TP * CC];  // 16384 B
    __shared__ __align__(16) unsigned short shs[TP * CC];  // 16384 B
    __shared__ __align__(16) unsigned short us [TP * RR];  //  8192 B
    const int tid  = threadIdx.x;
    const int b    = blockIdx.x >> 8;
    const int tile = blockIdx.x & (NT - 1);
    const int p0   = tile * TP;

    // ---- stage x/sh from packed scratch: coalesced uint loads, no cvt ----
    {
        const unsigned* wsrc = (const unsigned*)out + ((size_t)b * CC) * HWN + p0;
        const int p  = tid & 63;
        const int qh = tid >> 6;                    // 0..3
        #pragma unroll
        for (int it = 0; it < 4; ++it) {
            const int q  = it * 4 + qh;             // chunk 0..15 (8 channels each)
            const int sw = p * CC + ((q ^ (p & 15)) << 3);
            const unsigned* px_ = wsrc + (size_t)(q * 4) * HWN + p;
            const unsigned* ps_ = wsrc + (size_t)(64 + q * 4) * HWN + p;
            uint4 wx, wh;
            wx.x = px_[0]; wx.y = px_[HWN]; wx.z = px_[2 * HWN]; wx.w = px_[3 * HWN];
            wh.x = ps_[0]; wh.y = ps_[HWN]; wh.z = ps_[2 * HWN]; wh.w = ps_[3 * HWN];
            *(uint4*)&xs [sw] = wx;
            *(uint4*)&shs[sw] = wh;
        }
    }
    __syncthreads();

    const int wv = tid >> 6;        // wave 0..3
    const int ln = tid & 63;
    const int lp = ln & 15;         // m/n index within 16-tile
    const int lq = ln >> 4;         // quad

    f32x4 acc[2][4];                // [d-tile][p-tile], d in [wv*32, wv*32+32)
    #pragma unroll
    for (int i = 0; i < 2; ++i)
        #pragma unroll
        for (int j = 0; j < 4; ++j) acc[i][j] = (f32x4){0.f, 0.f, 0.f, 0.f};

    // ---- proj stage: acc = proj @ x  (K=128) ----
    {
        const int d0 = wv * 32;
        #pragma unroll
        for (int ks = 0; ks < 4; ++ks) {
            const int k0 = ks * 32 + lq * 8;
            const int ch = ks * 4 + lq;
            short8 a0 = *(const short8*)&projb[(d0 +      lp) * CC + k0];
            short8 a1 = *(const short8*)&projb[(d0 + 16 + lp) * CC + k0];
            #pragma unroll
            for (int pt = 0; pt < 4; ++pt) {
                short8 bf = *(const short8*)&xs[(pt * 16 + lp) * CC + ((ch ^ lp) << 3)];
                acc[0][pt] = __builtin_amdgcn_mfma_f32_16x16x32_bf16(a0, bf, acc[0][pt], 0, 0, 0);
                acc[1][pt] = __builtin_amdgcn_mfma_f32_16x16x32_bf16(a1, bf, acc[1][pt], 0, 0, 0);
            }
        }
        const float gs = gsum[b];
        #pragma unroll
        for (int i = 0; i < 2; ++i)
            #pragma unroll
            for (int j = 0; j < 4; ++j) acc[i][j] *= gs;
    }

    // ---- experts ----
    for (int e = 0; e < EE; ++e) {
        const float ge = gates[b * EE + e];
        if (ge == 0.f) continue;                       // block-uniform

        // stage A: a = W0 @ x, g = W1 @ sh  (rows wv*16..wv*16+16, K=128)
        f32x4 af[4], gf[4];
        #pragma unroll
        for (int pt = 0; pt < 4; ++pt) { af[pt] = (f32x4){0.f,0.f,0.f,0.f}; gf[pt] = (f32x4){0.f,0.f,0.f,0.f}; }
        const unsigned short* w0e = w0b + (size_t)(e * RR + wv * 16) * CC;
        const unsigned short* w1e = w1b + (size_t)(e * RR + wv * 16) * CC;
        #pragma unroll
        for (int ks = 0; ks < 4; ++ks) {
            const int k0 = ks * 32 + lq * 8;
            const int ch = ks * 4 + lq;
            short8 a0 = *(const short8*)&w0e[lp * CC + k0];
            short8 a1 = *(const short8*)&w1e[lp * CC + k0];
            #pragma unroll
            for (int pt = 0; pt < 4; ++pt) {
                const int sw = (pt * 16 + lp) * CC + ((ch ^ lp) << 3);
                short8 bx = *(const short8*)&xs [sw];
                short8 bs = *(const short8*)&shs[sw];
                af[pt] = __builtin_amdgcn_mfma_f32_16x16x32_bf16(a0, bx, af[pt], 0, 0, 0);
                gf[pt] = __builtin_amdgcn_mfma_f32_16x16x32_bf16(a1, bs, gf[pt], 0, 0, 0);
            }
        }
        __syncthreads();   // prev expert's us fully consumed
        // u = ge * a * silu(g) -> bf16 -> us (C layout row r = wv*16+lq*4+i)
        #pragma unroll
        for (int pt = 0; pt < 4; ++pt) {
            unsigned short t[4];
            #pragma unroll
            for (int i = 0; i < 4; ++i)
                t[i] = f2bf(ge * af[pt][i] * silu_f(gf[pt][i]));
            const int p = pt * 16 + lp;
            const int addr = p * RR + (((wv * 2 + (lq >> 1)) ^ (lp & 7)) << 3) + ((lq & 1) << 2);
            *(uint2*)&us[addr] = *(uint2*)t;
        }
        __syncthreads();   // us visible to all waves
        // stage B: acc += W2p[e] @ u   (K=64)
        const unsigned short* w2e = w2pb + (size_t)(e * CC + wv * 32) * RR;
        #pragma unroll
        for (int ks = 0; ks < 2; ++ks) {
            const int k0 = ks * 32 + lq * 8;
            const int ch = ks * 4 + lq;
            short8 a0 = *(const short8*)&w2e[lp * RR + k0];
            short8 a1 = *(const short8*)&w2e[(16 + lp) * RR + k0];
            #pragma unroll
            for (int pt = 0; pt < 4; ++pt) {
                short8 bu = *(const short8*)&us[(pt * 16 + lp) * RR + ((ch ^ (lp & 7)) << 3)];
                acc[0][pt] = __builtin_amdgcn_mfma_f32_16x16x32_bf16(a0, bu, acc[0][pt], 0, 0, 0);
                acc[1][pt] = __builtin_amdgcn_mfma_f32_16x16x32_bf16(a1, bu, acc[1][pt], 0, 0, 0);
            }
        }
    }

    // ---- store: lane holds (d = wv*32 + dt*16 + lq*4 + i, p = p0 + pt*16 + lp) ----
    {
        const int d0 = wv * 32;
        #pragma unroll
        for (int dt = 0; dt < 2; ++dt)
            #pragma unroll
            for (int pt = 0; pt < 4; ++pt) {
                float* ob = out + ((size_t)(b * CC + d0 + dt * 16 + lq * 4)) * HWN + p0 + pt * 16 + lp;
                #pragma unroll
                for (int i = 0; i < 4; ++i)
                    ob[(size_t)i * HWN] = acc[dt][pt][i];
            }
    }
}

// ---------- launch ----------
extern "C" void kernel_launch(void* const* d_in, const int* in_sizes, int n_in,
                              void* d_out, int out_size, void* d_ws, size_t ws_size,
                              hipStream_t stream) {
    const float* x    = (const float*)d_in[0];
    const float* shr  = (const float*)d_in[1];
    const float* mw1  = (const float*)d_in[2];
    const float* mb1  = (const float*)d_in[3];
    const float* mw2  = (const float*)d_in[4];
    const float* mb2  = (const float*)d_in[5];
    const float* gw   = (const float*)d_in[6];
    const float* fgw  = (const float*)d_in[7];
    const float* ew0  = (const float*)d_in[8];
    const float* ew1  = (const float*)d_in[9];
    const float* ew2  = (const float*)d_in[10];
    const float* pw   = (const float*)d_in[11];
    float* out = (float*)d_out;

    float* ws     = (float*)d_ws;
    float* fe0p   = ws + 0;        // 2048 f (2 band partials)
    float* poolp  = ws + 2048;     // 2048 f
    float* gates  = ws + 4096;     // 32 f
    float* gsum   = ws + 4128;     // 8 f
    float* dummy  = ws + 4136;     // 8 f (+pad to 4160)
    unsigned short* projb = (unsigned short*)(ws + 4160);   // 16384 us
    unsigned short* w0b   = projb + 16384;                  // 32768 us
    unsigned short* w1b   = w0b + 32768;                    // 32768 us
    unsigned short* w2pb  = w1b + 32768;                    // 32768 us

    k_prep   <<<PREP_GRID, 256, 0, stream>>>(x, shr, pw, ew0, ew1, ew2, mw1, mw2,
                                             gw, fgw, fe0p, poolp, projb, w0b, w1b, w2pb,
                                             out, dummy);
    k_route  <<<8,         256, 0, stream>>>(fe0p, poolp, mw1, mb1, mw2, mb2, gw, fgw, gates, gsum);
    k_experts<<<8 * NT,    256, 0, stream>>>(w0b, w1b, w2pb, projb, gates, gsum, out);
}